// Round 14
// baseline (364.426 us; speedup 1.0000x reference)
//
#include <hip/hip_runtime.h>
#include <hip/hip_bf16.h>
#include <hip/hip_cooperative_groups.h>

namespace cg = cooperative_groups;

#define N_NODES 10000
#define N_EDGES 70000
#define HEADS 6
#define MPAD 10112            // ceil(10000/128)*128
#define SELU_SCALE 1.0507009873554805f
#define SELU_ALPHA  1.6732632423543772f
#define NEG_SLOPE 0.2f

typedef __attribute__((ext_vector_type(8))) __bf16 bf16x8;
typedef __attribute__((ext_vector_type(4))) float f32x4;

__device__ __forceinline__ float selu_f(float x) {
    return x > 0.f ? SELU_SCALE * x : SELU_SCALE * SELU_ALPHA * (__expf(x) - 1.f);
}
__device__ __forceinline__ unsigned short f2bf(float f) {
    __hip_bfloat16 h = __float2bfloat16(f);
    return __builtin_bit_cast(unsigned short, h);
}
__device__ __forceinline__ float bf2f(unsigned short u) {
    unsigned int x = ((unsigned int)u) << 16;
    return __builtin_bit_cast(float, x);
}

// ---------------- cooperative CSR build: zero + count + scan + fill in ONE launch ----------
__global__ void csr_build_k(const int* __restrict__ srcv, const int* __restrict__ dstv,
                            int* __restrict__ counts, int* __restrict__ cursor,
                            int* __restrict__ offs, int* __restrict__ srcs) {
    cg::grid_group grid = cg::this_grid();
    const int gtid = blockIdx.x * blockDim.x + threadIdx.x;
    const int gsz = gridDim.x * blockDim.x;
    for (int i = gtid; i < N_NODES; i += gsz) { counts[i] = 0; cursor[i] = 0; }
    grid.sync();
    for (int e = gtid; e < N_EDGES; e += gsz) atomicAdd(&counts[dstv[e]], 1);
    grid.sync();
    if (blockIdx.x == 0) {
        __shared__ int part[512];
        int tid = threadIdx.x;
        const int per = (N_NODES + 511) / 512;   // 20
        int start = tid * per;
        int s = 0;
        for (int i = 0; i < per; ++i) { int idx = start + i; if (idx < N_NODES) s += counts[idx]; }
        part[tid] = s;
        __syncthreads();
        for (int off = 1; off < 512; off <<= 1) {
            int v = (tid >= off) ? part[tid - off] : 0;
            __syncthreads();
            part[tid] += v;
            __syncthreads();
        }
        int run = part[tid] - s;
        for (int i = 0; i < per; ++i) {
            int idx = start + i;
            if (idx < N_NODES) { offs[idx] = run; run += counts[idx]; }
        }
        if (tid == 0) offs[N_NODES] = part[511];
    }
    grid.sync();
    for (int e = gtid; e < N_EDGES; e += gsz) {
        int d = dstv[e];
        int pos = atomicAdd(&cursor[d], 1);
        srcs[offs[d] + pos] = srcv[e];
    }
}

// ---------------- fused prep + layer-1 proj: one wave per node ----------------
__global__ __launch_bounds__(256) void prep_proj_k(
    const float* __restrict__ data, const float* __restrict__ W, const float* __restrict__ b,
    float* __restrict__ coords0, unsigned short* __restrict__ t1,
    const float* __restrict__ wsf, const float* __restrict__ wdf,
    float* __restrict__ a_s, float* __restrict__ a_d) {
    const int wid = threadIdx.x >> 6, lane = threadIdx.x & 63;
    const int n = blockIdx.x * 4 + wid;
    if (n >= N_NODES) return;
    const int c0 = lane * 4;
    const float* dr = data + (size_t)n * 10;

    float vals[4];
#pragma unroll
    for (int q = 0; q < 4; ++q) {
        int c = c0 + q;
        if (c < 2) {
            vals[q] = dr[c];
        } else {
            int cc = c - 2;
            float acc = b[cc];
#pragma unroll
            for (int k = 0; k < 10; ++k) acc += dr[k] * W[k * 254 + cc];
            vals[q] = selu_f(acc);
        }
    }
    uint2 pk;
    pk.x = (unsigned int)f2bf(vals[0]) | ((unsigned int)f2bf(vals[1]) << 16);
    pk.y = (unsigned int)f2bf(vals[2]) | ((unsigned int)f2bf(vals[3]) << 16);
    *(uint2*)(t1 + (size_t)n * 256 + c0) = pk;
    if (lane == 0) {
        coords0[2 * n] = vals[0];
        coords0[2 * n + 1] = vals[1];
    }

    float s[HEADS] = {}, d[HEADS] = {};
#pragma unroll
    for (int q = 0; q < 4; ++q) {
        float v = bf2f(f2bf(vals[q]));
        const float* ws = wsf + (size_t)(c0 + q) * HEADS;
        const float* wd = wdf + (size_t)(c0 + q) * HEADS;
#pragma unroll
        for (int h = 0; h < HEADS; ++h) {
            s[h] += v * ws[h];
            d[h] += v * wd[h];
        }
    }
#pragma unroll
    for (int off = 32; off > 0; off >>= 1) {
#pragma unroll
        for (int h = 0; h < HEADS; ++h) {
            s[h] += __shfl_xor(s[h], off);
            d[h] += __shfl_xor(d[h], off);
        }
    }
    if (lane == 0) {
#pragma unroll
        for (int h = 0; h < HEADS; ++h) {
            a_s[n * HEADS + h] = s[h];
            a_d[n * HEADS + h] = d[h];
        }
    }
}

// ---------------- fold (all 4 layers) + Vt build (3 layers) in ONE launch ----------------
// blocks [0,1728): fold, one wave per (layer,k,h) pair (4 waves/block)
// blocks [1728,2160): convv, 64x64 transpose tiles
__global__ __launch_bounds__(256) void weights_prep_k(
    const float* __restrict__ W0, const float* __restrict__ s0v, const float* __restrict__ d0v,
    const float* __restrict__ W1, const float* __restrict__ s1v, const float* __restrict__ d1v,
    const float* __restrict__ W2, const float* __restrict__ s2v, const float* __restrict__ d2v,
    const float* __restrict__ W3, const float* __restrict__ s3v, const float* __restrict__ d3v,
    float* __restrict__ wsf0, float* __restrict__ wdf0,
    float* __restrict__ wsf1, float* __restrict__ wdf1,
    float* __restrict__ wsf2, float* __restrict__ wdf2,
    float* __restrict__ wsf3, float* __restrict__ wdf3,
    unsigned short* __restrict__ Vt0, unsigned short* __restrict__ Vt1,
    unsigned short* __restrict__ Vt2) {
    __shared__ float tile[64][65];
    const int bidg = blockIdx.x;
    if (bidg < 1728) {
        const int wid = threadIdx.x >> 6, lane = threadIdx.x & 63;
        int bid = bidg * 4 + wid;            // pair index 0..6911
        const float* W; const float* sv; const float* dv; float* ws; float* wd;
        int K, C, pair;
        if (bid < 1536)      { W = W0; sv = s0v; dv = d0v; ws = wsf0; wd = wdf0; K = 256; C = 508; pair = bid; }
        else if (bid < 4608) { W = W1; sv = s1v; dv = d1v; ws = wsf1; wd = wdf1; K = 512; C = 250; pair = bid - 1536; }
        else if (bid < 6144) { W = W2; sv = s2v; dv = d2v; ws = wsf2; wd = wdf2; K = 256; C = 120; pair = bid - 4608; }
        else                 { W = W3; sv = s3v; dv = d3v; ws = wsf3; wd = wdf3; K = 128; C = 20;  pair = bid - 6144; }
        int k = pair / HEADS, h = pair % HEADS;
        const float* wr = W + (size_t)k * (HEADS * C) + h * C;
        const float* sr = sv + h * C;
        const float* dr = dv + h * C;
        float s = 0.f, d = 0.f;
        for (int c = lane; c < C; c += 64) {
            float w = wr[c];
            s += w * sr[c];
            d += w * dr[c];
        }
#pragma unroll
        for (int off = 32; off > 0; off >>= 1) {
            s += __shfl_xor(s, off);
            d += __shfl_xor(d, off);
        }
        if (lane == 0) { ws[pair] = s; wd[pair] = d; }
    } else {
        int bid = bidg - 1728;
        const float* W; unsigned short* Vt; int K, C, K6, bid2, ktiles;
        if (bid < 192)      { W = W0; Vt = Vt0; K = 256; C = 508; K6 = 1536; bid2 = bid;       ktiles = 24; }
        else if (bid < 384) { W = W1; Vt = Vt1; K = 512; C = 250; K6 = 3072; bid2 = bid - 192; ktiles = 48; }
        else                { W = W2; Vt = Vt2; K = 256; C = 120; K6 = 1536; bid2 = bid - 384; ktiles = 24; }
        int kb = bid2 % ktiles, cb = bid2 / ktiles;
        const int tx = threadIdx.x & 63;
        const int ty = threadIdx.x >> 6;
        const int k0 = kb * 64;
        const int c0 = cb * 64;
        for (int i = ty; i < 64; i += 4) {
            int kk = k0 + i;
            int h = kk / K, k = kk - h * K;
            int c = c0 + tx;
            tile[i][tx] = (c < C) ? W[(size_t)k * (HEADS * C) + h * C + c] : 0.f;
        }
        __syncthreads();
        for (int i = ty; i < 64; i += 4) {
            int c = c0 + i;
            Vt[(size_t)c * K6 + k0 + tx] = f2bf(tile[tx][i]);
        }
    }
}

// ---------------- split-K MFMA GEMM, double-buffered LDS + counted vmcnt prefetch ----------
__global__ __launch_bounds__(256) void gemm_split_k(
    const unsigned short* __restrict__ A,
    const unsigned short* __restrict__ Bt,
    unsigned short* __restrict__ part,
    int Kpitch, int klen, int Npad) {
    __shared__ unsigned short lds[2][16384];
    const int tid = threadIdx.x;
    const int lane = tid & 63, wid = tid >> 6;
    const int wm = wid >> 1, wn = wid & 1;
    const int m0 = blockIdx.y * 128;
    const int n0 = blockIdx.x * 128;
    const int kz = blockIdx.z;
    const int kbeg = kz * klen;
    const int nt = klen >> 6;

    f32x4 acc[4][4] = {};

    const unsigned short* gsrc[8];
    unsigned ldsoff[8];
#pragma unroll
    for (int i = 0; i < 8; ++i) {
        const int half = i >> 2;
        const int slot = (i & 3) * 256 + tid;
        const int r = slot >> 3;
        const int c16 = slot & 7;
        const int ksl = c16 ^ (r & 7);
        gsrc[i] = (half ? (Bt + (size_t)(n0 + r) * Kpitch) : (A + (size_t)(m0 + r) * Kpitch)) + ksl * 8;
        ldsoff[i] = (unsigned)(half * 8192 + ((i & 3) * 256 + wid * 64) * 8);
    }

    auto stage = [&](int kt, int buf) {
#pragma unroll
        for (int i = 0; i < 8; ++i) {
            __builtin_amdgcn_global_load_lds(
                (const __attribute__((address_space(1))) unsigned int*)(gsrc[i] + kt),
                (__attribute__((address_space(3))) unsigned int*)(&lds[buf][ldsoff[i]]),
                16, 0, 0);
        }
    };

    stage(kbeg, 0);
    for (int t = 0; t < nt; ++t) {
        const int cur = t & 1;
        if (t + 1 < nt) {
            stage(kbeg + (t + 1) * 64, cur ^ 1);
            asm volatile("s_waitcnt vmcnt(8)" ::: "memory");
        } else {
            asm volatile("s_waitcnt vmcnt(0)" ::: "memory");
        }
        __builtin_amdgcn_sched_barrier(0);
        __builtin_amdgcn_s_barrier();
        const char* base = (const char*)(&lds[cur][0]);
#pragma unroll
        for (int kc = 0; kc < 2; ++kc) {
            const int xo = (((kc * 4 + (lane >> 4)) ^ (lane & 7)) << 4);
            bf16x8 aop[4], bop[4];
#pragma unroll
            for (int f = 0; f < 4; ++f) {
                const int rA = wm * 64 + f * 16 + (lane & 15);
                bop[f] = *(const bf16x8*)(base + rA * 128 + xo);
                const int rB = wn * 64 + f * 16 + (lane & 15);
                aop[f] = *(const bf16x8*)(base + 16384 + rB * 128 + xo);
            }
#pragma unroll
            for (int fm = 0; fm < 4; ++fm)
#pragma unroll
                for (int fn = 0; fn < 4; ++fn)
                    acc[fm][fn] = __builtin_amdgcn_mfma_f32_16x16x32_bf16(
                        aop[fn], bop[fm], acc[fm][fn], 0, 0, 0);
        }
        __builtin_amdgcn_s_barrier();
    }

    unsigned short* pbase = part + (size_t)kz * MPAD * Npad;
    const int mrow = m0 + wm * 64 + (lane & 15);
    const int ncol = n0 + wn * 64 + ((lane >> 4) * 4);
#pragma unroll
    for (int fm = 0; fm < 4; ++fm) {
#pragma unroll
        for (int fn = 0; fn < 4; ++fn) {
            f32x4 v = acc[fm][fn];
            unsigned int u0 = (unsigned int)f2bf(v.x) | ((unsigned int)f2bf(v.y) << 16);
            unsigned int u1 = (unsigned int)f2bf(v.z) | ((unsigned int)f2bf(v.w) << 16);
            uint2 pk = make_uint2(u0, u1);
            *(uint2*)&pbase[(size_t)(mrow + fm * 16) * Npad + ncol + fn * 16] = pk;
        }
    }
}

// ---------------- fused reduce-partials + selu + next-layer proj: one wave per node --------
template<int KN>
__global__ __launch_bounds__(256) void reduceproj_k(
    const unsigned short* __restrict__ part, int KS, int Npad, int off,
    unsigned short* __restrict__ tnext,
    const float* __restrict__ wsf, const float* __restrict__ wdf,
    float* __restrict__ a_s, float* __restrict__ a_d) {
    const int wid = threadIdx.x >> 6, lane = threadIdx.x & 63;
    const int n = blockIdx.x * 4 + wid;
    if (n >= N_NODES) return;
    constexpr int KPL = KN / 64;
    const int c0 = lane * KPL;
    unsigned short* row = tnext + (size_t)n * KN;

    float vals[KPL];
#pragma unroll
    for (int q = 0; q < KPL; q += 2) {
        int c = c0 + q;
        if (c < off) {
            unsigned int u = *(const unsigned int*)(row + c);
            vals[q] = bf2f((unsigned short)(u & 0xffff));
            vals[q + 1] = bf2f((unsigned short)(u >> 16));
        } else {
            int cp = c - off;
            float s0 = 0.f, s1 = 0.f;
            for (int kz = 0; kz < KS; ++kz) {
                unsigned int u = *(const unsigned int*)(part + (size_t)kz * MPAD * Npad
                                                       + (size_t)n * Npad + cp);
                s0 += bf2f((unsigned short)(u & 0xffff));
                s1 += bf2f((unsigned short)(u >> 16));
            }
            float o0 = selu_f(s0 * (1.f / 6.f));
            float o1 = selu_f(s1 * (1.f / 6.f));
            vals[q] = o0; vals[q + 1] = o1;
            *(unsigned int*)(row + c) =
                (unsigned int)f2bf(o0) | ((unsigned int)f2bf(o1) << 16);
        }
    }

    float s[HEADS] = {}, d[HEADS] = {};
#pragma unroll
    for (int q = 0; q < KPL; ++q) {
        int c = c0 + q;
        float v = vals[q];
        const float* ws = wsf + (size_t)c * HEADS;
        const float* wd = wdf + (size_t)c * HEADS;
#pragma unroll
        for (int h = 0; h < HEADS; ++h) {
            s[h] += v * ws[h];
            d[h] += v * wd[h];
        }
    }
#pragma unroll
    for (int off2 = 32; off2 > 0; off2 >>= 1) {
#pragma unroll
        for (int h = 0; h < HEADS; ++h) {
            s[h] += __shfl_xor(s[h], off2);
            d[h] += __shfl_xor(d[h], off2);
        }
    }
    if (lane == 0) {
#pragma unroll
        for (int h = 0; h < HEADS; ++h) {
            a_s[n * HEADS + h] = s[h];
            a_d[n * HEADS + h] = d[h];
        }
    }
}

// ---------------- fused softmax + aggregate + move_coords: ONE WAVE PER NODE ---------------
template<int KT>
__global__ __launch_bounds__(256) void attn_agg_move_k(
    const float* __restrict__ a_s, const float* __restrict__ a_d,
    const int* __restrict__ srcs, const int* __restrict__ offs,
    const unsigned short* __restrict__ t_in, unsigned short* __restrict__ thagg,
    const float* __restrict__ cprev, const int* __restrict__ bd,
    float* __restrict__ cout, unsigned short* __restrict__ tnext, int ld,
    const float* __restrict__ xA, int offA,
    const float* __restrict__ xB, int offB) {
    const int wid = threadIdx.x >> 6, lane = threadIdx.x & 63;
    const int n = blockIdx.x * 4 + wid;
    if (n >= N_NODES) return;
    const int r0 = offs[n], r1 = offs[n + 1];
    const int deg = r1 - r0;

    float ad[HEADS];
#pragma unroll
    for (int h = 0; h < HEADS; ++h) ad[h] = a_d[n * HEADS + h];

    constexpr int KPL = (KT > 0) ? (KT / 64) : 1;
    float acc[HEADS][KPL] = {};
    float cx = 0.f, cy = 0.f;

    if (deg <= 64) {
        const bool ok = lane < deg;
        const int mysrc = ok ? srcs[r0 + lane] : 0;
        float lv[HEADS], mm[HEADS], ss[HEADS], myal[HEADS];
#pragma unroll
        for (int h = 0; h < HEADS; ++h) {
            float v = -1e30f;
            if (ok) {
                v = a_s[mysrc * HEADS + h] + ad[h];
                v = v > 0.f ? v : NEG_SLOPE * v;
            }
            lv[h] = v;       // cache logit: no second gather
            mm[h] = v;
        }
#pragma unroll
        for (int off = 32; off > 0; off >>= 1)
#pragma unroll
            for (int h = 0; h < HEADS; ++h) mm[h] = fmaxf(mm[h], __shfl_xor(mm[h], off));
#pragma unroll
        for (int h = 0; h < HEADS; ++h) {
            myal[h] = ok ? __expf(lv[h] - mm[h]) : 0.f;
            ss[h] = myal[h];
        }
#pragma unroll
        for (int off = 32; off > 0; off >>= 1)
#pragma unroll
            for (int h = 0; h < HEADS; ++h) ss[h] += __shfl_xor(ss[h], off);
        float am = 0.f;
#pragma unroll
        for (int h = 0; h < HEADS; ++h) {
            float rdh = ss[h] > 0.f ? 1.f / ss[h] : 0.f;
            myal[h] *= rdh;
            am += myal[h];
        }
        if (ok) {
            am *= (1.f / 6.f);
            cx = am * cprev[2 * mysrc];
            cy = am * cprev[2 * mysrc + 1];
        }
        if constexpr (KT > 0) {
            for (int j = 0; j < deg; ++j) {
                int src = __shfl(mysrc, j);
                float al[HEADS];
#pragma unroll
                for (int h = 0; h < HEADS; ++h) al[h] = __shfl(myal[h], j);
                if constexpr (KT == 512) {
                    uint4 u = *(const uint4*)(t_in + (size_t)src * 512 + lane * 8);
                    float tv[8];
                    tv[0] = bf2f((unsigned short)(u.x & 0xffff)); tv[1] = bf2f((unsigned short)(u.x >> 16));
                    tv[2] = bf2f((unsigned short)(u.y & 0xffff)); tv[3] = bf2f((unsigned short)(u.y >> 16));
                    tv[4] = bf2f((unsigned short)(u.z & 0xffff)); tv[5] = bf2f((unsigned short)(u.z >> 16));
                    tv[6] = bf2f((unsigned short)(u.w & 0xffff)); tv[7] = bf2f((unsigned short)(u.w >> 16));
#pragma unroll
                    for (int h = 0; h < HEADS; ++h)
#pragma unroll
                        for (int q = 0; q < 8; ++q) acc[h][q] += al[h] * tv[q];
                } else {
                    uint2 u = *(const uint2*)(t_in + (size_t)src * 256 + lane * 4);
                    float tv[4];
                    tv[0] = bf2f((unsigned short)(u.x & 0xffff)); tv[1] = bf2f((unsigned short)(u.x >> 16));
                    tv[2] = bf2f((unsigned short)(u.y & 0xffff)); tv[3] = bf2f((unsigned short)(u.y >> 16));
#pragma unroll
                    for (int h = 0; h < HEADS; ++h)
#pragma unroll
                        for (int q = 0; q < 4; ++q) acc[h][q] += al[h] * tv[q];
                }
            }
        }
    } else {
        float mm[HEADS], ss[HEADS];
#pragma unroll
        for (int h = 0; h < HEADS; ++h) { mm[h] = -1e30f; ss[h] = 0.f; }
        for (int base = r0; base < r1; base += 64) {
            int i = base + lane;
            if (i < r1) {
                int src = srcs[i];
#pragma unroll
                for (int h = 0; h < HEADS; ++h) {
                    float v = a_s[src * HEADS + h] + ad[h];
                    v = v > 0.f ? v : NEG_SLOPE * v;
                    float nm = fmaxf(mm[h], v);
                    ss[h] = ss[h] * __expf(mm[h] - nm) + __expf(v - nm);
                    mm[h] = nm;
                }
            }
        }
#pragma unroll
        for (int off = 32; off > 0; off >>= 1) {
#pragma unroll
            for (int h = 0; h < HEADS; ++h) {
                float mo = __shfl_xor(mm[h], off);
                float so = __shfl_xor(ss[h], off);
                float nm = fmaxf(mm[h], mo);
                ss[h] = ss[h] * __expf(mm[h] - nm) + so * __expf(mo - nm);
                mm[h] = nm;
            }
        }
        float rd[HEADS];
#pragma unroll
        for (int h = 0; h < HEADS; ++h) rd[h] = ss[h] > 0.f ? 1.f / ss[h] : 0.f;

        for (int base = r0; base < r1; base += 64) {
            int i = base + lane;
            bool ok = i < r1;
            int mysrc = ok ? srcs[i] : 0;
            float myal[HEADS];
#pragma unroll
            for (int h = 0; h < HEADS; ++h) myal[h] = 0.f;
            if (ok) {
                float am = 0.f;
#pragma unroll
                for (int h = 0; h < HEADS; ++h) {
                    float v = a_s[mysrc * HEADS + h] + ad[h];
                    v = v > 0.f ? v : NEG_SLOPE * v;
                    float a = __expf(v - mm[h]) * rd[h];
                    myal[h] = a;
                    am += a;
                }
                am *= (1.f / 6.f);
                cx += am * cprev[2 * mysrc];
                cy += am * cprev[2 * mysrc + 1];
            }
            if constexpr (KT > 0) {
                int cnt = min(64, r1 - base);
                for (int j = 0; j < cnt; ++j) {
                    int src = __shfl(mysrc, j);
                    float al[HEADS];
#pragma unroll
                    for (int h = 0; h < HEADS; ++h) al[h] = __shfl(myal[h], j);
                    if constexpr (KT == 512) {
                        uint4 u = *(const uint4*)(t_in + (size_t)src * 512 + lane * 8);
                        float tv[8];
                        tv[0] = bf2f((unsigned short)(u.x & 0xffff)); tv[1] = bf2f((unsigned short)(u.x >> 16));
                        tv[2] = bf2f((unsigned short)(u.y & 0xffff)); tv[3] = bf2f((unsigned short)(u.y >> 16));
                        tv[4] = bf2f((unsigned short)(u.z & 0xffff)); tv[5] = bf2f((unsigned short)(u.z >> 16));
                        tv[6] = bf2f((unsigned short)(u.w & 0xffff)); tv[7] = bf2f((unsigned short)(u.w >> 16));
#pragma unroll
                        for (int h = 0; h < HEADS; ++h)
#pragma unroll
                            for (int q = 0; q < 8; ++q) acc[h][q] += al[h] * tv[q];
                    } else {
                        uint2 u = *(const uint2*)(t_in + (size_t)src * 256 + lane * 4);
                        float tv[4];
                        tv[0] = bf2f((unsigned short)(u.x & 0xffff)); tv[1] = bf2f((unsigned short)(u.x >> 16));
                        tv[2] = bf2f((unsigned short)(u.y & 0xffff)); tv[3] = bf2f((unsigned short)(u.y >> 16));
#pragma unroll
                        for (int h = 0; h < HEADS; ++h)
#pragma unroll
                            for (int q = 0; q < 4; ++q) acc[h][q] += al[h] * tv[q];
                    }
                }
            }
        }
    }

    if constexpr (KT == 512) {
#pragma unroll
        for (int h = 0; h < HEADS; ++h) {
            uint4 pk;
            pk.x = (unsigned int)f2bf(acc[h][0]) | ((unsigned int)f2bf(acc[h][1]) << 16);
            pk.y = (unsigned int)f2bf(acc[h][2]) | ((unsigned int)f2bf(acc[h][3]) << 16);
            pk.z = (unsigned int)f2bf(acc[h][4]) | ((unsigned int)f2bf(acc[h][5]) << 16);
            pk.w = (unsigned int)f2bf(acc[h][6]) | ((unsigned int)f2bf(acc[h][7]) << 16);
            *(uint4*)(thagg + (size_t)n * 3072 + h * 512 + lane * 8) = pk;
        }
    } else if constexpr (KT == 256) {
#pragma unroll
        for (int h = 0; h < HEADS; ++h) {
            uint2 pk;
            pk.x = (unsigned int)f2bf(acc[h][0]) | ((unsigned int)f2bf(acc[h][1]) << 16);
            pk.y = (unsigned int)f2bf(acc[h][2]) | ((unsigned int)f2bf(acc[h][3]) << 16);
            *(uint2*)(thagg + (size_t)n * 1536 + h * 256 + lane * 4) = pk;
        }
    }
#pragma unroll
    for (int off = 32; off > 0; off >>= 1) {
        cx += __shfl_xor(cx, off);
        cy += __shfl_xor(cy, off);
    }
    if (lane == 0) {
        float px = cprev[2 * n], py = cprev[2 * n + 1];
        float ocx, ocy;
        if (bd[n] != 0) { ocx = px; ocy = py; }
        else { ocx = cx; ocy = cy; }
        cout[2 * n] = ocx; cout[2 * n + 1] = ocy;
        if (tnext) {
            unsigned short* row = tnext + (size_t)n * ld;
            row[0] = f2bf(ocx); row[1] = f2bf(ocy);
            row[2] = f2bf(px);  row[3] = f2bf(py);
            if (xA) { row[offA] = f2bf(xA[2 * n]); row[offA + 1] = f2bf(xA[2 * n + 1]); }
            if (xB) { row[offB] = f2bf(xB[2 * n]); row[offB + 1] = f2bf(xB[2 * n + 1]); }
        }
    }
}

static inline int cdiv(int a, int b) { return (a + b - 1) / b; }

extern "C" void kernel_launch(void* const* d_in, const int* in_sizes, int n_in,
                              void* d_out, int out_size, void* d_ws, size_t ws_size,
                              hipStream_t stream) {
    const float* data = (const float*)d_in[0];
    const int* eidx = (const int*)d_in[1];
    const int* bd = (const int*)d_in[2];
    const float* W_lin = (const float*)d_in[4];
    const float* b_lin = (const float*)d_in[5];
    const float* Wl[4]  = {(const float*)d_in[6],  (const float*)d_in[9],
                           (const float*)d_in[12], (const float*)d_in[15]};
    const float* Asrc[4] = {(const float*)d_in[7],  (const float*)d_in[10],
                            (const float*)d_in[13], (const float*)d_in[16]};
    const float* Adst[4] = {(const float*)d_in[8],  (const float*)d_in[11],
                            (const float*)d_in[14], (const float*)d_in[17]};
    const int Kd[4] = {256, 512, 256, 128};
    const int Cpadd[4] = {512, 256, 128, 0};
    const int KSd[4] = {2, 4, 4, 0};

    const int* srcv = eidx;
    const int* dstv = eidx + N_EDGES;

    char* p = (char*)d_ws;
    auto alloc = [&](size_t bytes) -> void* {
        void* r = (void*)p;
        p += (bytes + 255) & ~(size_t)255;
        return r;
    };
    unsigned short* tb1 = (unsigned short*)alloc((size_t)MPAD * 256 * 2);
    unsigned short* tb2 = (unsigned short*)alloc((size_t)MPAD * 512 * 2);
    unsigned short* tb3 = (unsigned short*)alloc((size_t)MPAD * 256 * 2);
    unsigned short* tb4 = (unsigned short*)alloc((size_t)MPAD * 128 * 2);
    unsigned short* thagg = (unsigned short*)alloc((size_t)MPAD * 3072 * 2);
    unsigned short* VtL[3];
    VtL[0] = (unsigned short*)alloc((size_t)512 * 1536 * 2);
    VtL[1] = (unsigned short*)alloc((size_t)256 * 3072 * 2);
    VtL[2] = (unsigned short*)alloc((size_t)128 * 1536 * 2);
    unsigned short* partb = (unsigned short*)alloc((size_t)8 * MPAD * 256 * 2);
    float* coords0 = (float*)alloc((size_t)N_NODES * 2 * 4);
    float* c1 = (float*)alloc((size_t)N_NODES * 2 * 4);
    float* c2 = (float*)alloc((size_t)N_NODES * 2 * 4);
    float* c3 = (float*)alloc((size_t)N_NODES * 2 * 4);
    float* a_s = (float*)alloc((size_t)N_NODES * HEADS * 4);
    float* a_d = (float*)alloc((size_t)N_NODES * HEADS * 4);
    float* wsfL[4]; float* wdfL[4];
    wsfL[0] = (float*)alloc(1536 * 4); wdfL[0] = (float*)alloc(1536 * 4);
    wsfL[1] = (float*)alloc(3072 * 4); wdfL[1] = (float*)alloc(3072 * 4);
    wsfL[2] = (float*)alloc(1536 * 4); wdfL[2] = (float*)alloc(1536 * 4);
    wsfL[3] = (float*)alloc(768 * 4);  wdfL[3] = (float*)alloc(768 * 4);
    int* counts = (int*)alloc((size_t)N_NODES * 4);
    int* cursor = (int*)alloc((size_t)N_NODES * 4);
    int* offs = (int*)alloc((size_t)(N_NODES + 1) * 4);
    int* srcs = (int*)alloc((size_t)N_EDGES * 4);

    // cooperative CSR build: zero + count + scan + fill, one launch
    {
        void* args[] = {(void*)&srcv, (void*)&dstv, (void*)&counts,
                        (void*)&cursor, (void*)&offs, (void*)&srcs};
        hipLaunchCooperativeKernel((void*)csr_build_k, dim3(160), dim3(512), args, 0, stream);
    }

    weights_prep_k<<<2160, 256, 0, stream>>>(
        Wl[0], Asrc[0], Adst[0], Wl[1], Asrc[1], Adst[1],
        Wl[2], Asrc[2], Adst[2], Wl[3], Asrc[3], Adst[3],
        wsfL[0], wdfL[0], wsfL[1], wdfL[1], wsfL[2], wdfL[2], wsfL[3], wdfL[3],
        VtL[0], VtL[1], VtL[2]);
    prep_proj_k<<<cdiv(N_NODES, 4), 256, 0, stream>>>(
        data, W_lin, b_lin, coords0, tb1, wsfL[0], wdfL[0], a_s, a_d);

    unsigned short* tin[4]   = {tb1, tb2, tb3, tb4};
    unsigned short* tnext[4] = {tb2, tb3, tb4, nullptr};
    int ldn[4]  = {512, 256, 128, 0};
    int foff[4] = {4, 6, 8, 0};
    float* cprev[4] = {coords0, c1, c2, c3};
    float* cout[4]  = {c1, c2, c3, (float*)d_out};
    const float* xAv[4] = {nullptr, coords0, c1, nullptr};
    int offAv[4] = {0, 4, 4, 0};
    const float* xBv[4] = {nullptr, nullptr, coords0, nullptr};
    int offBv[4] = {0, 0, 6, 0};

    for (int l = 0; l < 4; ++l) {
        int K = Kd[l], Cpad = Cpadd[l], KS = KSd[l];
        int K6 = K * HEADS;

        if (l == 3) {
            attn_agg_move_k<0><<<cdiv(N_NODES, 4), 256, 0, stream>>>(
                a_s, a_d, srcs, offs, tin[l], nullptr,
                cprev[l], bd, cout[l], tnext[l], ldn[l],
                xAv[l], offAv[l], xBv[l], offBv[l]);
        } else if (K == 512) {
            attn_agg_move_k<512><<<cdiv(N_NODES, 4), 256, 0, stream>>>(
                a_s, a_d, srcs, offs, tin[l], thagg,
                cprev[l], bd, cout[l], tnext[l], ldn[l],
                xAv[l], offAv[l], xBv[l], offBv[l]);
        } else {
            attn_agg_move_k<256><<<cdiv(N_NODES, 4), 256, 0, stream>>>(
                a_s, a_d, srcs, offs, tin[l], thagg,
                cprev[l], bd, cout[l], tnext[l], ldn[l],
                xAv[l], offAv[l], xBv[l], offBv[l]);
        }

        if (l < 3) {
            int klen = K6 / KS;
            gemm_split_k<<<dim3(Cpad / 128, MPAD / 128, KS), 256, 0, stream>>>(
                thagg, VtL[l], partb, K6, klen, Cpad);
            if (ldn[l] == 512) {
                reduceproj_k<512><<<cdiv(N_NODES, 4), 256, 0, stream>>>(
                    partb, KS, Cpad, foff[l], tnext[l], wsfL[l + 1], wdfL[l + 1], a_s, a_d);
            } else if (ldn[l] == 256) {
                reduceproj_k<256><<<cdiv(N_NODES, 4), 256, 0, stream>>>(
                    partb, KS, Cpad, foff[l], tnext[l], wsfL[l + 1], wdfL[l + 1], a_s, a_d);
            } else {
                reduceproj_k<128><<<cdiv(N_NODES, 4), 256, 0, stream>>>(
                    partb, KS, Cpad, foff[l], tnext[l], wsfL[l + 1], wdfL[l + 1], a_s, a_d);
            }
        }
    }
}

// Round 15
// 299.280 us; speedup vs baseline: 1.2177x; 1.2177x over previous
//
#include <hip/hip_runtime.h>
#include <hip/hip_bf16.h>

#define N_NODES 10000
#define N_EDGES 70000
#define HEADS 6
#define MPAD 10112            // ceil(10000/128)*128
#define SELU_SCALE 1.0507009873554805f
#define SELU_ALPHA  1.6732632423543772f
#define NEG_SLOPE 0.2f

typedef __attribute__((ext_vector_type(8))) __bf16 bf16x8;
typedef __attribute__((ext_vector_type(4))) float f32x4;

__device__ __forceinline__ float selu_f(float x) {
    return x > 0.f ? SELU_SCALE * x : SELU_SCALE * SELU_ALPHA * (__expf(x) - 1.f);
}
__device__ __forceinline__ unsigned short f2bf(float f) {
    __hip_bfloat16 h = __float2bfloat16(f);
    return __builtin_bit_cast(unsigned short, h);
}
__device__ __forceinline__ float bf2f(unsigned short u) {
    unsigned int x = ((unsigned int)u) << 16;
    return __builtin_bit_cast(float, x);
}

// ---------------- CSR build (4 small launches — cooperative version was 5x slower) --------
__global__ void count_edges_k(const int* __restrict__ dstv, int* __restrict__ counts) {
    int e = blockIdx.x * blockDim.x + threadIdx.x;
    if (e < N_EDGES) atomicAdd(&counts[dstv[e]], 1);
}

__global__ __launch_bounds__(1024) void scan_k(const int* __restrict__ counts, int* __restrict__ offs) {
    __shared__ int part[1024];
    int tid = threadIdx.x;
    const int per = (N_NODES + 1023) / 1024;  // 10
    int start = tid * per;
    int s = 0;
    for (int i = 0; i < per; ++i) { int idx = start + i; if (idx < N_NODES) s += counts[idx]; }
    part[tid] = s;
    __syncthreads();
    for (int off = 1; off < 1024; off <<= 1) {
        int v = (tid >= off) ? part[tid - off] : 0;
        __syncthreads();
        part[tid] += v;
        __syncthreads();
    }
    int run = part[tid] - s;
    for (int i = 0; i < per; ++i) {
        int idx = start + i;
        if (idx < N_NODES) { offs[idx] = run; run += counts[idx]; }
    }
    if (tid == 0) offs[N_NODES] = part[1023];
}

__global__ void fill_csr_k(const int* __restrict__ srcv, const int* __restrict__ dstv,
                           const int* __restrict__ offs,
                           int* __restrict__ cursor, int* __restrict__ srcs) {
    int e = blockIdx.x * blockDim.x + threadIdx.x;
    if (e < N_EDGES) {
        int d = dstv[e];
        int pos = atomicAdd(&cursor[d], 1);
        srcs[offs[d] + pos] = srcv[e];
    }
}

// ---------------- fused prep + layer-1 proj: one wave per node ----------------
__global__ __launch_bounds__(256) void prep_proj_k(
    const float* __restrict__ data, const float* __restrict__ W, const float* __restrict__ b,
    float* __restrict__ coords0, unsigned short* __restrict__ t1,
    const float* __restrict__ wsf, const float* __restrict__ wdf,
    float* __restrict__ a_s, float* __restrict__ a_d) {
    const int wid = threadIdx.x >> 6, lane = threadIdx.x & 63;
    const int n = blockIdx.x * 4 + wid;
    if (n >= N_NODES) return;
    const int c0 = lane * 4;
    const float* dr = data + (size_t)n * 10;

    float vals[4];
#pragma unroll
    for (int q = 0; q < 4; ++q) {
        int c = c0 + q;
        if (c < 2) {
            vals[q] = dr[c];
        } else {
            int cc = c - 2;
            float acc = b[cc];
#pragma unroll
            for (int k = 0; k < 10; ++k) acc += dr[k] * W[k * 254 + cc];
            vals[q] = selu_f(acc);
        }
    }
    uint2 pk;
    pk.x = (unsigned int)f2bf(vals[0]) | ((unsigned int)f2bf(vals[1]) << 16);
    pk.y = (unsigned int)f2bf(vals[2]) | ((unsigned int)f2bf(vals[3]) << 16);
    *(uint2*)(t1 + (size_t)n * 256 + c0) = pk;
    if (lane == 0) {
        coords0[2 * n] = vals[0];
        coords0[2 * n + 1] = vals[1];
    }

    float s[HEADS] = {}, d[HEADS] = {};
#pragma unroll
    for (int q = 0; q < 4; ++q) {
        float v = bf2f(f2bf(vals[q]));
        const float* ws = wsf + (size_t)(c0 + q) * HEADS;
        const float* wd = wdf + (size_t)(c0 + q) * HEADS;
#pragma unroll
        for (int h = 0; h < HEADS; ++h) {
            s[h] += v * ws[h];
            d[h] += v * wd[h];
        }
    }
#pragma unroll
    for (int off = 32; off > 0; off >>= 1) {
#pragma unroll
        for (int h = 0; h < HEADS; ++h) {
            s[h] += __shfl_xor(s[h], off);
            d[h] += __shfl_xor(d[h], off);
        }
    }
    if (lane == 0) {
#pragma unroll
        for (int h = 0; h < HEADS; ++h) {
            a_s[n * HEADS + h] = s[h];
            a_d[n * HEADS + h] = d[h];
        }
    }
}

// ---------------- fold (all 4 layers) + Vt build (3 layers) in ONE launch ----------------
__global__ __launch_bounds__(256) void weights_prep_k(
    const float* __restrict__ W0, const float* __restrict__ s0v, const float* __restrict__ d0v,
    const float* __restrict__ W1, const float* __restrict__ s1v, const float* __restrict__ d1v,
    const float* __restrict__ W2, const float* __restrict__ s2v, const float* __restrict__ d2v,
    const float* __restrict__ W3, const float* __restrict__ s3v, const float* __restrict__ d3v,
    float* __restrict__ wsf0, float* __restrict__ wdf0,
    float* __restrict__ wsf1, float* __restrict__ wdf1,
    float* __restrict__ wsf2, float* __restrict__ wdf2,
    float* __restrict__ wsf3, float* __restrict__ wdf3,
    unsigned short* __restrict__ Vt0, unsigned short* __restrict__ Vt1,
    unsigned short* __restrict__ Vt2) {
    __shared__ float tile[64][65];
    const int bidg = blockIdx.x;
    if (bidg < 1728) {
        const int wid = threadIdx.x >> 6, lane = threadIdx.x & 63;
        int bid = bidg * 4 + wid;            // pair index 0..6911
        const float* W; const float* sv; const float* dv; float* ws; float* wd;
        int K, C, pair;
        if (bid < 1536)      { W = W0; sv = s0v; dv = d0v; ws = wsf0; wd = wdf0; K = 256; C = 508; pair = bid; }
        else if (bid < 4608) { W = W1; sv = s1v; dv = d1v; ws = wsf1; wd = wdf1; K = 512; C = 250; pair = bid - 1536; }
        else if (bid < 6144) { W = W2; sv = s2v; dv = d2v; ws = wsf2; wd = wdf2; K = 256; C = 120; pair = bid - 4608; }
        else                 { W = W3; sv = s3v; dv = d3v; ws = wsf3; wd = wdf3; K = 128; C = 20;  pair = bid - 6144; }
        int k = pair / HEADS, h = pair % HEADS;
        const float* wr = W + (size_t)k * (HEADS * C) + h * C;
        const float* sr = sv + h * C;
        const float* dr = dv + h * C;
        float s = 0.f, d = 0.f;
        for (int c = lane; c < C; c += 64) {
            float w = wr[c];
            s += w * sr[c];
            d += w * dr[c];
        }
#pragma unroll
        for (int off = 32; off > 0; off >>= 1) {
            s += __shfl_xor(s, off);
            d += __shfl_xor(d, off);
        }
        if (lane == 0) { ws[pair] = s; wd[pair] = d; }
    } else {
        int bid = bidg - 1728;
        const float* W; unsigned short* Vt; int K, C, K6, bid2, ktiles;
        if (bid < 192)      { W = W0; Vt = Vt0; K = 256; C = 508; K6 = 1536; bid2 = bid;       ktiles = 24; }
        else if (bid < 384) { W = W1; Vt = Vt1; K = 512; C = 250; K6 = 3072; bid2 = bid - 192; ktiles = 48; }
        else                { W = W2; Vt = Vt2; K = 256; C = 120; K6 = 1536; bid2 = bid - 384; ktiles = 24; }
        int kb = bid2 % ktiles, cb = bid2 / ktiles;
        const int tx = threadIdx.x & 63;
        const int ty = threadIdx.x >> 6;
        const int k0 = kb * 64;
        const int c0 = cb * 64;
        for (int i = ty; i < 64; i += 4) {
            int kk = k0 + i;
            int h = kk / K, k = kk - h * K;
            int c = c0 + tx;
            tile[i][tx] = (c < C) ? W[(size_t)k * (HEADS * C) + h * C + c] : 0.f;
        }
        __syncthreads();
        for (int i = ty; i < 64; i += 4) {
            int c = c0 + i;
            Vt[(size_t)c * K6 + k0 + tx] = f2bf(tile[tx][i]);
        }
    }
}

// ---------------- split-K MFMA GEMM, double-buffered LDS + counted vmcnt prefetch ----------
__global__ __launch_bounds__(256) void gemm_split_k(
    const unsigned short* __restrict__ A,
    const unsigned short* __restrict__ Bt,
    unsigned short* __restrict__ part,
    int Kpitch, int klen, int Npad) {
    __shared__ unsigned short lds[2][16384];
    const int tid = threadIdx.x;
    const int lane = tid & 63, wid = tid >> 6;
    const int wm = wid >> 1, wn = wid & 1;
    const int m0 = blockIdx.y * 128;
    const int n0 = blockIdx.x * 128;
    const int kz = blockIdx.z;
    const int kbeg = kz * klen;
    const int nt = klen >> 6;

    f32x4 acc[4][4] = {};

    const unsigned short* gsrc[8];
    unsigned ldsoff[8];
#pragma unroll
    for (int i = 0; i < 8; ++i) {
        const int half = i >> 2;
        const int slot = (i & 3) * 256 + tid;
        const int r = slot >> 3;
        const int c16 = slot & 7;
        const int ksl = c16 ^ (r & 7);
        gsrc[i] = (half ? (Bt + (size_t)(n0 + r) * Kpitch) : (A + (size_t)(m0 + r) * Kpitch)) + ksl * 8;
        ldsoff[i] = (unsigned)(half * 8192 + ((i & 3) * 256 + wid * 64) * 8);
    }

    auto stage = [&](int kt, int buf) {
#pragma unroll
        for (int i = 0; i < 8; ++i) {
            __builtin_amdgcn_global_load_lds(
                (const __attribute__((address_space(1))) unsigned int*)(gsrc[i] + kt),
                (__attribute__((address_space(3))) unsigned int*)(&lds[buf][ldsoff[i]]),
                16, 0, 0);
        }
    };

    stage(kbeg, 0);
    for (int t = 0; t < nt; ++t) {
        const int cur = t & 1;
        if (t + 1 < nt) {
            stage(kbeg + (t + 1) * 64, cur ^ 1);
            asm volatile("s_waitcnt vmcnt(8)" ::: "memory");
        } else {
            asm volatile("s_waitcnt vmcnt(0)" ::: "memory");
        }
        __builtin_amdgcn_sched_barrier(0);
        __builtin_amdgcn_s_barrier();
        const char* base = (const char*)(&lds[cur][0]);
#pragma unroll
        for (int kc = 0; kc < 2; ++kc) {
            const int xo = (((kc * 4 + (lane >> 4)) ^ (lane & 7)) << 4);
            bf16x8 aop[4], bop[4];
#pragma unroll
            for (int f = 0; f < 4; ++f) {
                const int rA = wm * 64 + f * 16 + (lane & 15);
                bop[f] = *(const bf16x8*)(base + rA * 128 + xo);
                const int rB = wn * 64 + f * 16 + (lane & 15);
                aop[f] = *(const bf16x8*)(base + 16384 + rB * 128 + xo);
            }
#pragma unroll
            for (int fm = 0; fm < 4; ++fm)
#pragma unroll
                for (int fn = 0; fn < 4; ++fn)
                    acc[fm][fn] = __builtin_amdgcn_mfma_f32_16x16x32_bf16(
                        aop[fn], bop[fm], acc[fm][fn], 0, 0, 0);
        }
        __builtin_amdgcn_s_barrier();
    }

    unsigned short* pbase = part + (size_t)kz * MPAD * Npad;
    const int mrow = m0 + wm * 64 + (lane & 15);
    const int ncol = n0 + wn * 64 + ((lane >> 4) * 4);
#pragma unroll
    for (int fm = 0; fm < 4; ++fm) {
#pragma unroll
        for (int fn = 0; fn < 4; ++fn) {
            f32x4 v = acc[fm][fn];
            unsigned int u0 = (unsigned int)f2bf(v.x) | ((unsigned int)f2bf(v.y) << 16);
            unsigned int u1 = (unsigned int)f2bf(v.z) | ((unsigned int)f2bf(v.w) << 16);
            uint2 pk = make_uint2(u0, u1);
            *(uint2*)&pbase[(size_t)(mrow + fm * 16) * Npad + ncol + fn * 16] = pk;
        }
    }
}

// ---------------- fused reduce-partials + selu + next-layer proj: one wave per node --------
template<int KN>
__global__ __launch_bounds__(256) void reduceproj_k(
    const unsigned short* __restrict__ part, int KS, int Npad, int off,
    unsigned short* __restrict__ tnext,
    const float* __restrict__ wsf, const float* __restrict__ wdf,
    float* __restrict__ a_s, float* __restrict__ a_d) {
    const int wid = threadIdx.x >> 6, lane = threadIdx.x & 63;
    const int n = blockIdx.x * 4 + wid;
    if (n >= N_NODES) return;
    constexpr int KPL = KN / 64;
    const int c0 = lane * KPL;
    unsigned short* row = tnext + (size_t)n * KN;

    float vals[KPL];
#pragma unroll
    for (int q = 0; q < KPL; q += 2) {
        int c = c0 + q;
        if (c < off) {
            unsigned int u = *(const unsigned int*)(row + c);
            vals[q] = bf2f((unsigned short)(u & 0xffff));
            vals[q + 1] = bf2f((unsigned short)(u >> 16));
        } else {
            int cp = c - off;
            float s0 = 0.f, s1 = 0.f;
            for (int kz = 0; kz < KS; ++kz) {
                unsigned int u = *(const unsigned int*)(part + (size_t)kz * MPAD * Npad
                                                       + (size_t)n * Npad + cp);
                s0 += bf2f((unsigned short)(u & 0xffff));
                s1 += bf2f((unsigned short)(u >> 16));
            }
            float o0 = selu_f(s0 * (1.f / 6.f));
            float o1 = selu_f(s1 * (1.f / 6.f));
            vals[q] = o0; vals[q + 1] = o1;
            *(unsigned int*)(row + c) =
                (unsigned int)f2bf(o0) | ((unsigned int)f2bf(o1) << 16);
        }
    }

    float s[HEADS] = {}, d[HEADS] = {};
#pragma unroll
    for (int q = 0; q < KPL; ++q) {
        int c = c0 + q;
        float v = vals[q];
        const float* ws = wsf + (size_t)c * HEADS;
        const float* wd = wdf + (size_t)c * HEADS;
#pragma unroll
        for (int h = 0; h < HEADS; ++h) {
            s[h] += v * ws[h];
            d[h] += v * wd[h];
        }
    }
#pragma unroll
    for (int off2 = 32; off2 > 0; off2 >>= 1) {
#pragma unroll
        for (int h = 0; h < HEADS; ++h) {
            s[h] += __shfl_xor(s[h], off2);
            d[h] += __shfl_xor(d[h], off2);
        }
    }
    if (lane == 0) {
#pragma unroll
        for (int h = 0; h < HEADS; ++h) {
            a_s[n * HEADS + h] = s[h];
            a_d[n * HEADS + h] = d[h];
        }
    }
}

// ---------------- fused softmax + aggregate + move_coords: ONE WAVE PER NODE ---------------
template<int KT>
__global__ __launch_bounds__(256) void attn_agg_move_k(
    const float* __restrict__ a_s, const float* __restrict__ a_d,
    const int* __restrict__ srcs, const int* __restrict__ offs,
    const unsigned short* __restrict__ t_in, unsigned short* __restrict__ thagg,
    const float* __restrict__ cprev, const int* __restrict__ bd,
    float* __restrict__ cout, unsigned short* __restrict__ tnext, int ld,
    const float* __restrict__ xA, int offA,
    const float* __restrict__ xB, int offB) {
    const int wid = threadIdx.x >> 6, lane = threadIdx.x & 63;
    const int n = blockIdx.x * 4 + wid;
    if (n >= N_NODES) return;
    const int r0 = offs[n], r1 = offs[n + 1];
    const int deg = r1 - r0;

    float ad[HEADS];
#pragma unroll
    for (int h = 0; h < HEADS; ++h) ad[h] = a_d[n * HEADS + h];

    constexpr int KPL = (KT > 0) ? (KT / 64) : 1;
    float acc[HEADS][KPL] = {};
    float cx = 0.f, cy = 0.f;

    if (deg <= 64) {
        const bool ok = lane < deg;
        const int mysrc = ok ? srcs[r0 + lane] : 0;
        float lv[HEADS], mm[HEADS], ss[HEADS], myal[HEADS];
#pragma unroll
        for (int h = 0; h < HEADS; ++h) {
            float v = -1e30f;
            if (ok) {
                v = a_s[mysrc * HEADS + h] + ad[h];
                v = v > 0.f ? v : NEG_SLOPE * v;
            }
            lv[h] = v;       // cache logit: no second gather
            mm[h] = v;
        }
#pragma unroll
        for (int off = 32; off > 0; off >>= 1)
#pragma unroll
            for (int h = 0; h < HEADS; ++h) mm[h] = fmaxf(mm[h], __shfl_xor(mm[h], off));
#pragma unroll
        for (int h = 0; h < HEADS; ++h) {
            myal[h] = ok ? __expf(lv[h] - mm[h]) : 0.f;
            ss[h] = myal[h];
        }
#pragma unroll
        for (int off = 32; off > 0; off >>= 1)
#pragma unroll
            for (int h = 0; h < HEADS; ++h) ss[h] += __shfl_xor(ss[h], off);
        float am = 0.f;
#pragma unroll
        for (int h = 0; h < HEADS; ++h) {
            float rdh = ss[h] > 0.f ? 1.f / ss[h] : 0.f;
            myal[h] *= rdh;
            am += myal[h];
        }
        if (ok) {
            am *= (1.f / 6.f);
            cx = am * cprev[2 * mysrc];
            cy = am * cprev[2 * mysrc + 1];
        }
        if constexpr (KT > 0) {
            for (int j = 0; j < deg; ++j) {
                int src = __shfl(mysrc, j);
                float al[HEADS];
#pragma unroll
                for (int h = 0; h < HEADS; ++h) al[h] = __shfl(myal[h], j);
                if constexpr (KT == 512) {
                    uint4 u = *(const uint4*)(t_in + (size_t)src * 512 + lane * 8);
                    float tv[8];
                    tv[0] = bf2f((unsigned short)(u.x & 0xffff)); tv[1] = bf2f((unsigned short)(u.x >> 16));
                    tv[2] = bf2f((unsigned short)(u.y & 0xffff)); tv[3] = bf2f((unsigned short)(u.y >> 16));
                    tv[4] = bf2f((unsigned short)(u.z & 0xffff)); tv[5] = bf2f((unsigned short)(u.z >> 16));
                    tv[6] = bf2f((unsigned short)(u.w & 0xffff)); tv[7] = bf2f((unsigned short)(u.w >> 16));
#pragma unroll
                    for (int h = 0; h < HEADS; ++h)
#pragma unroll
                        for (int q = 0; q < 8; ++q) acc[h][q] += al[h] * tv[q];
                } else {
                    uint2 u = *(const uint2*)(t_in + (size_t)src * 256 + lane * 4);
                    float tv[4];
                    tv[0] = bf2f((unsigned short)(u.x & 0xffff)); tv[1] = bf2f((unsigned short)(u.x >> 16));
                    tv[2] = bf2f((unsigned short)(u.y & 0xffff)); tv[3] = bf2f((unsigned short)(u.y >> 16));
#pragma unroll
                    for (int h = 0; h < HEADS; ++h)
#pragma unroll
                        for (int q = 0; q < 4; ++q) acc[h][q] += al[h] * tv[q];
                }
            }
        }
    } else {
        float mm[HEADS], ss[HEADS];
#pragma unroll
        for (int h = 0; h < HEADS; ++h) { mm[h] = -1e30f; ss[h] = 0.f; }
        for (int base = r0; base < r1; base += 64) {
            int i = base + lane;
            if (i < r1) {
                int src = srcs[i];
#pragma unroll
                for (int h = 0; h < HEADS; ++h) {
                    float v = a_s[src * HEADS + h] + ad[h];
                    v = v > 0.f ? v : NEG_SLOPE * v;
                    float nm = fmaxf(mm[h], v);
                    ss[h] = ss[h] * __expf(mm[h] - nm) + __expf(v - nm);
                    mm[h] = nm;
                }
            }
        }
#pragma unroll
        for (int off = 32; off > 0; off >>= 1) {
#pragma unroll
            for (int h = 0; h < HEADS; ++h) {
                float mo = __shfl_xor(mm[h], off);
                float so = __shfl_xor(ss[h], off);
                float nm = fmaxf(mm[h], mo);
                ss[h] = ss[h] * __expf(mm[h] - nm) + so * __expf(mo - nm);
                mm[h] = nm;
            }
        }
        float rd[HEADS];
#pragma unroll
        for (int h = 0; h < HEADS; ++h) rd[h] = ss[h] > 0.f ? 1.f / ss[h] : 0.f;

        for (int base = r0; base < r1; base += 64) {
            int i = base + lane;
            bool ok = i < r1;
            int mysrc = ok ? srcs[i] : 0;
            float myal[HEADS];
#pragma unroll
            for (int h = 0; h < HEADS; ++h) myal[h] = 0.f;
            if (ok) {
                float am = 0.f;
#pragma unroll
                for (int h = 0; h < HEADS; ++h) {
                    float v = a_s[mysrc * HEADS + h] + ad[h];
                    v = v > 0.f ? v : NEG_SLOPE * v;
                    float a = __expf(v - mm[h]) * rd[h];
                    myal[h] = a;
                    am += a;
                }
                am *= (1.f / 6.f);
                cx += am * cprev[2 * mysrc];
                cy += am * cprev[2 * mysrc + 1];
            }
            if constexpr (KT > 0) {
                int cnt = min(64, r1 - base);
                for (int j = 0; j < cnt; ++j) {
                    int src = __shfl(mysrc, j);
                    float al[HEADS];
#pragma unroll
                    for (int h = 0; h < HEADS; ++h) al[h] = __shfl(myal[h], j);
                    if constexpr (KT == 512) {
                        uint4 u = *(const uint4*)(t_in + (size_t)src * 512 + lane * 8);
                        float tv[8];
                        tv[0] = bf2f((unsigned short)(u.x & 0xffff)); tv[1] = bf2f((unsigned short)(u.x >> 16));
                        tv[2] = bf2f((unsigned short)(u.y & 0xffff)); tv[3] = bf2f((unsigned short)(u.y >> 16));
                        tv[4] = bf2f((unsigned short)(u.z & 0xffff)); tv[5] = bf2f((unsigned short)(u.z >> 16));
                        tv[6] = bf2f((unsigned short)(u.w & 0xffff)); tv[7] = bf2f((unsigned short)(u.w >> 16));
#pragma unroll
                        for (int h = 0; h < HEADS; ++h)
#pragma unroll
                            for (int q = 0; q < 8; ++q) acc[h][q] += al[h] * tv[q];
                    } else {
                        uint2 u = *(const uint2*)(t_in + (size_t)src * 256 + lane * 4);
                        float tv[4];
                        tv[0] = bf2f((unsigned short)(u.x & 0xffff)); tv[1] = bf2f((unsigned short)(u.x >> 16));
                        tv[2] = bf2f((unsigned short)(u.y & 0xffff)); tv[3] = bf2f((unsigned short)(u.y >> 16));
#pragma unroll
                        for (int h = 0; h < HEADS; ++h)
#pragma unroll
                            for (int q = 0; q < 4; ++q) acc[h][q] += al[h] * tv[q];
                    }
                }
            }
        }
    }

    if constexpr (KT == 512) {
#pragma unroll
        for (int h = 0; h < HEADS; ++h) {
            uint4 pk;
            pk.x = (unsigned int)f2bf(acc[h][0]) | ((unsigned int)f2bf(acc[h][1]) << 16);
            pk.y = (unsigned int)f2bf(acc[h][2]) | ((unsigned int)f2bf(acc[h][3]) << 16);
            pk.z = (unsigned int)f2bf(acc[h][4]) | ((unsigned int)f2bf(acc[h][5]) << 16);
            pk.w = (unsigned int)f2bf(acc[h][6]) | ((unsigned int)f2bf(acc[h][7]) << 16);
            *(uint4*)(thagg + (size_t)n * 3072 + h * 512 + lane * 8) = pk;
        }
    } else if constexpr (KT == 256) {
#pragma unroll
        for (int h = 0; h < HEADS; ++h) {
            uint2 pk;
            pk.x = (unsigned int)f2bf(acc[h][0]) | ((unsigned int)f2bf(acc[h][1]) << 16);
            pk.y = (unsigned int)f2bf(acc[h][2]) | ((unsigned int)f2bf(acc[h][3]) << 16);
            *(uint2*)(thagg + (size_t)n * 1536 + h * 256 + lane * 4) = pk;
        }
    }
#pragma unroll
    for (int off = 32; off > 0; off >>= 1) {
        cx += __shfl_xor(cx, off);
        cy += __shfl_xor(cy, off);
    }
    if (lane == 0) {
        float px = cprev[2 * n], py = cprev[2 * n + 1];
        float ocx, ocy;
        if (bd[n] != 0) { ocx = px; ocy = py; }
        else { ocx = cx; ocy = cy; }
        cout[2 * n] = ocx; cout[2 * n + 1] = ocy;
        if (tnext) {
            unsigned short* row = tnext + (size_t)n * ld;
            row[0] = f2bf(ocx); row[1] = f2bf(ocy);
            row[2] = f2bf(px);  row[3] = f2bf(py);
            if (xA) { row[offA] = f2bf(xA[2 * n]); row[offA + 1] = f2bf(xA[2 * n + 1]); }
            if (xB) { row[offB] = f2bf(xB[2 * n]); row[offB + 1] = f2bf(xB[2 * n + 1]); }
        }
    }
}

static inline int cdiv(int a, int b) { return (a + b - 1) / b; }

extern "C" void kernel_launch(void* const* d_in, const int* in_sizes, int n_in,
                              void* d_out, int out_size, void* d_ws, size_t ws_size,
                              hipStream_t stream) {
    const float* data = (const float*)d_in[0];
    const int* eidx = (const int*)d_in[1];
    const int* bd = (const int*)d_in[2];
    const float* W_lin = (const float*)d_in[4];
    const float* b_lin = (const float*)d_in[5];
    const float* Wl[4]  = {(const float*)d_in[6],  (const float*)d_in[9],
                           (const float*)d_in[12], (const float*)d_in[15]};
    const float* Asrc[4] = {(const float*)d_in[7],  (const float*)d_in[10],
                            (const float*)d_in[13], (const float*)d_in[16]};
    const float* Adst[4] = {(const float*)d_in[8],  (const float*)d_in[11],
                            (const float*)d_in[14], (const float*)d_in[17]};
    const int Kd[4] = {256, 512, 256, 128};
    const int Cpadd[4] = {512, 256, 128, 0};
    const int KSd[4] = {2, 4, 4, 0};

    const int* srcv = eidx;
    const int* dstv = eidx + N_EDGES;

    char* p = (char*)d_ws;
    auto alloc = [&](size_t bytes) -> void* {
        void* r = (void*)p;
        p += (bytes + 255) & ~(size_t)255;
        return r;
    };
    unsigned short* tb1 = (unsigned short*)alloc((size_t)MPAD * 256 * 2);
    unsigned short* tb2 = (unsigned short*)alloc((size_t)MPAD * 512 * 2);
    unsigned short* tb3 = (unsigned short*)alloc((size_t)MPAD * 256 * 2);
    unsigned short* tb4 = (unsigned short*)alloc((size_t)MPAD * 128 * 2);
    unsigned short* thagg = (unsigned short*)alloc((size_t)MPAD * 3072 * 2);
    unsigned short* VtL[3];
    VtL[0] = (unsigned short*)alloc((size_t)512 * 1536 * 2);
    VtL[1] = (unsigned short*)alloc((size_t)256 * 3072 * 2);
    VtL[2] = (unsigned short*)alloc((size_t)128 * 1536 * 2);
    unsigned short* partb = (unsigned short*)alloc((size_t)8 * MPAD * 256 * 2);
    float* coords0 = (float*)alloc((size_t)N_NODES * 2 * 4);
    float* c1 = (float*)alloc((size_t)N_NODES * 2 * 4);
    float* c2 = (float*)alloc((size_t)N_NODES * 2 * 4);
    float* c3 = (float*)alloc((size_t)N_NODES * 2 * 4);
    float* a_s = (float*)alloc((size_t)N_NODES * HEADS * 4);
    float* a_d = (float*)alloc((size_t)N_NODES * HEADS * 4);
    float* wsfL[4]; float* wdfL[4];
    wsfL[0] = (float*)alloc(1536 * 4); wdfL[0] = (float*)alloc(1536 * 4);
    wsfL[1] = (float*)alloc(3072 * 4); wdfL[1] = (float*)alloc(3072 * 4);
    wsfL[2] = (float*)alloc(1536 * 4); wdfL[2] = (float*)alloc(1536 * 4);
    wsfL[3] = (float*)alloc(768 * 4);  wdfL[3] = (float*)alloc(768 * 4);
    int* counts = (int*)alloc((size_t)N_NODES * 4);   // counts+cursor adjacent: one memset
    int* cursor = (int*)alloc((size_t)N_NODES * 4);
    int* offs = (int*)alloc((size_t)(N_NODES + 1) * 4);
    int* srcs = (int*)alloc((size_t)N_EDGES * 4);

    hipMemsetAsync(counts, 0, (size_t)((char*)offs - (char*)counts), stream);
    count_edges_k<<<cdiv(N_EDGES, 256), 256, 0, stream>>>(dstv, counts);
    scan_k<<<1, 1024, 0, stream>>>(counts, offs);
    fill_csr_k<<<cdiv(N_EDGES, 256), 256, 0, stream>>>(srcv, dstv, offs, cursor, srcs);

    weights_prep_k<<<2160, 256, 0, stream>>>(
        Wl[0], Asrc[0], Adst[0], Wl[1], Asrc[1], Adst[1],
        Wl[2], Asrc[2], Adst[2], Wl[3], Asrc[3], Adst[3],
        wsfL[0], wdfL[0], wsfL[1], wdfL[1], wsfL[2], wdfL[2], wsfL[3], wdfL[3],
        VtL[0], VtL[1], VtL[2]);
    prep_proj_k<<<cdiv(N_NODES, 4), 256, 0, stream>>>(
        data, W_lin, b_lin, coords0, tb1, wsfL[0], wdfL[0], a_s, a_d);

    unsigned short* tin[4]   = {tb1, tb2, tb3, tb4};
    unsigned short* tnext[4] = {tb2, tb3, tb4, nullptr};
    int ldn[4]  = {512, 256, 128, 0};
    int foff[4] = {4, 6, 8, 0};
    float* cprev[4] = {coords0, c1, c2, c3};
    float* cout[4]  = {c1, c2, c3, (float*)d_out};
    const float* xAv[4] = {nullptr, coords0, c1, nullptr};
    int offAv[4] = {0, 4, 4, 0};
    const float* xBv[4] = {nullptr, nullptr, coords0, nullptr};
    int offBv[4] = {0, 0, 6, 0};

    for (int l = 0; l < 4; ++l) {
        int K = Kd[l], Cpad = Cpadd[l], KS = KSd[l];
        int K6 = K * HEADS;

        if (l == 3) {
            attn_agg_move_k<0><<<cdiv(N_NODES, 4), 256, 0, stream>>>(
                a_s, a_d, srcs, offs, tin[l], nullptr,
                cprev[l], bd, cout[l], tnext[l], ldn[l],
                xAv[l], offAv[l], xBv[l], offBv[l]);
        } else if (K == 512) {
            attn_agg_move_k<512><<<cdiv(N_NODES, 4), 256, 0, stream>>>(
                a_s, a_d, srcs, offs, tin[l], thagg,
                cprev[l], bd, cout[l], tnext[l], ldn[l],
                xAv[l], offAv[l], xBv[l], offBv[l]);
        } else {
            attn_agg_move_k<256><<<cdiv(N_NODES, 4), 256, 0, stream>>>(
                a_s, a_d, srcs, offs, tin[l], thagg,
                cprev[l], bd, cout[l], tnext[l], ldn[l],
                xAv[l], offAv[l], xBv[l], offBv[l]);
        }

        if (l < 3) {
            int klen = K6 / KS;
            gemm_split_k<<<dim3(Cpad / 128, MPAD / 128, KS), 256, 0, stream>>>(
                thagg, VtL[l], partb, K6, klen, Cpad);
            if (ldn[l] == 512) {
                reduceproj_k<512><<<cdiv(N_NODES, 4), 256, 0, stream>>>(
                    partb, KS, Cpad, foff[l], tnext[l], wsfL[l + 1], wdfL[l + 1], a_s, a_d);
            } else if (ldn[l] == 256) {
                reduceproj_k<256><<<cdiv(N_NODES, 4), 256, 0, stream>>>(
                    partb, KS, Cpad, foff[l], tnext[l], wsfL[l + 1], wdfL[l + 1], a_s, a_d);
            } else {
                reduceproj_k<128><<<cdiv(N_NODES, 4), 256, 0, stream>>>(
                    partb, KS, Cpad, foff[l], tnext[l], wsfL[l + 1], wdfL[l + 1], a_s, a_d);
            }
        }
    }
}